// Round 1
// baseline (345.589 us; speedup 1.0000x reference)
//
#include <hip/hip_runtime.h>

// SSM4D: causal depthwise conv1d, B=16, C=1024, T=3000, K=24, fp32.
// y[b,c,t] = sum_{d=0..23} w[c][d] * x[b,c,t-d],  w[c][d] = kern[c][K-1-d]
// kern[c][k] = beta[c] * exp(log(max(alpha[c],1e-6))*k) * cos4(theta[c]*k)

#define KSZ   24
#define TILE  1024
#define BLOCK 256
#define T_LEN 3000
#define C_CH  1024
#define B_N   16

__device__ __forceinline__ float cos_approx(float v) {
    float v2 = v * v;
    return 1.0f - 0.5f * v2 + (v2 * v2) * (1.0f / 24.0f);
}

__global__ __launch_bounds__(BLOCK) void ssm4d_conv(
        const float* __restrict__ x,
        const float* __restrict__ alpha,
        const float* __restrict__ beta,
        const float* __restrict__ theta,
        float* __restrict__ y) {
    // s[m] = x[t0 - KSZ + m]; main tile lives at s[KSZ + j] (96B offset -> 16B aligned)
    __shared__ __align__(16) float s[KSZ + TILE];
    __shared__ float sw[KSZ];

    const int tile = blockIdx.x;            // 0..2
    const int row  = blockIdx.y;            // b*C + c
    const int c    = row & (C_CH - 1);
    const long base = (long)row * T_LEN;
    const int t0  = tile * TILE;
    const int tid = threadIdx.x;

    // lanes 0..23: compute this channel's flipped weights + load halo
    if (tid < KSZ) {
        const int k = (KSZ - 1) - tid;      // kernel tap index (flip for causal FIR)
        const float a  = fmaxf(alpha[c], 1e-6f);
        const float la = logf(a);
        const float dec = expf(la * (float)k);
        const float ph  = cos_approx(theta[c] * (float)k);
        sw[tid] = beta[c] * dec * ph;

        const int th = t0 - KSZ + tid;      // halo: x[t0-24 .. t0-1] (+1 unused lead)
        s[tid] = (th >= 0) ? x[base + th] : 0.0f;
    }

    const int t = t0 + 4 * tid;             // T % 4 == 0: float4 fully in or out
    if (t < T_LEN) {
        *(float4*)(s + KSZ + 4 * tid) = *(const float4*)(x + base + t);
    }
    __syncthreads();
    if (t >= T_LEN) return;

    // window: arr[p] = s[4*tid + p] = x[t0 - 24 + 4*tid + p], p = 0..27
    float arr[28];
#pragma unroll
    for (int q = 0; q < 7; ++q) {
        float4 v = *(const float4*)(s + 4 * tid + 4 * q);   // lane-contiguous b128
        arr[4 * q + 0] = v.x; arr[4 * q + 1] = v.y;
        arr[4 * q + 2] = v.z; arr[4 * q + 3] = v.w;
    }
    float wr[KSZ];
#pragma unroll
    for (int d = 0; d < KSZ; ++d) wr[d] = sw[d];

    float a0 = 0.f, a1 = 0.f, a2 = 0.f, a3 = 0.f;
#pragma unroll
    for (int d = 0; d < KSZ; ++d) {
        // output t+m uses x[t+m-d] = arr[24 + m - d]
        a0 = fmaf(wr[d], arr[24 + 0 - d], a0);
        a1 = fmaf(wr[d], arr[24 + 1 - d], a1);
        a2 = fmaf(wr[d], arr[24 + 2 - d], a2);
        a3 = fmaf(wr[d], arr[24 + 3 - d], a3);
    }
    *(float4*)(y + base + t) = make_float4(a0, a1, a2, a3);
}

extern "C" void kernel_launch(void* const* d_in, const int* in_sizes, int n_in,
                              void* d_out, int out_size, void* d_ws, size_t ws_size,
                              hipStream_t stream) {
    const float* x     = (const float*)d_in[0];
    const float* alpha = (const float*)d_in[1];
    const float* beta  = (const float*)d_in[2];
    const float* theta = (const float*)d_in[3];
    float* y = (float*)d_out;

    dim3 grid((T_LEN + TILE - 1) / TILE, B_N * C_CH);   // (3, 16384)
    ssm4d_conv<<<grid, BLOCK, 0, stream>>>(x, alpha, beta, theta, y);
}

// Round 2
// 336.492 us; speedup vs baseline: 1.0270x; 1.0270x over previous
//
#include <hip/hip_runtime.h>

// SSM4D: causal depthwise conv1d, B=16, C=1024, T=3000, K=24, fp32.
// y[b,c,t] = sum_{d=0..23} w[c][d] * x[b,c,t-d],  w[c][d] = kern[c][K-1-d]
// kern[c][k] = beta[c] * exp(log(max(alpha[c],1e-6))*k) * cos4(theta[c]*k)
//
// R2: LDS-free. R1 was LDS-pipe-bound (3.3e7 conflict cycles: stride-16B
// ds_read_b128 + 96 broadcast ds_read_b32/block for weights). Now: weights
// precomputed to d_ws by a tiny pre-kernel; x windows read directly from
// global (L1 absorbs the ~4x lane overlap); 8 outputs/thread.

#define KSZ   24
#define T_LEN 3000
#define C_CH  1024
#define B_N   16
#define OPT   8            // outputs per thread
#define TPB   128
#define TILE  (TPB * OPT)  // 1024

__device__ __forceinline__ float cos_approx(float v) {
    float v2 = v * v;
    return 1.0f - 0.5f * v2 + (v2 * v2) * (1.0f / 24.0f);
}

__global__ void ssm4d_weights(const float* __restrict__ alpha,
                              const float* __restrict__ beta,
                              const float* __restrict__ theta,
                              float* __restrict__ w) {
    const int i = blockIdx.x * blockDim.x + threadIdx.x;   // i = c*24 + d
    if (i >= C_CH * KSZ) return;
    const int c = i / KSZ;
    const int d = i - c * KSZ;
    const int k = (KSZ - 1) - d;                           // flip for causal FIR
    const float a   = fmaxf(alpha[c], 1e-6f);
    const float dec = expf(logf(a) * (float)k);
    w[i] = beta[c] * dec * cos_approx(theta[c] * (float)k);
}

__global__ __launch_bounds__(TPB) void ssm4d_conv(
        const float* __restrict__ x,
        const float* __restrict__ w,
        float* __restrict__ y) {
    const int row  = blockIdx.y;                 // b*C + c
    const int c    = row & (C_CH - 1);
    const long base = (long)row * T_LEN;
    const int t    = blockIdx.x * TILE + threadIdx.x * OPT;  // first output
    if (t >= T_LEN) return;                      // tail block: tid>=119 idle

    // 24 weights: block-uniform addresses -> L1/L2 broadcast, 6x float4
    float wr[KSZ];
    const float4* wp = (const float4*)(w + c * KSZ);
#pragma unroll
    for (int q = 0; q < KSZ / 4; ++q) {
        float4 v = wp[q];
        wr[4 * q + 0] = v.x; wr[4 * q + 1] = v.y;
        wr[4 * q + 2] = v.z; wr[4 * q + 3] = v.w;
    }

    // window arr[p] = x[t - 24 + p], p = 0..31 (arr[0] unused; kept for alignment)
    float arr[KSZ + OPT];
    if (t >= KSZ) {
        const float4* xp = (const float4*)(x + base + t - KSZ);  // 16B aligned
#pragma unroll
        for (int q = 0; q < (KSZ + OPT) / 4; ++q) {
            float4 v = xp[q];
            arr[4 * q + 0] = v.x; arr[4 * q + 1] = v.y;
            arr[4 * q + 2] = v.z; arr[4 * q + 3] = v.w;
        }
    } else {
        // only threads 0..2 of tile-0 blocks: causal zero-pad
#pragma unroll
        for (int p = 0; p < KSZ + OPT; ++p) {
            const int idx = t - KSZ + p;
            arr[p] = (idx >= 0) ? x[base + idx] : 0.0f;
        }
    }

    float acc[OPT];
#pragma unroll
    for (int m = 0; m < OPT; ++m) acc[m] = 0.0f;
#pragma unroll
    for (int d = 0; d < KSZ; ++d) {
#pragma unroll
        for (int m = 0; m < OPT; ++m)
            acc[m] = fmaf(wr[d], arr[KSZ + m - d], acc[m]);  // y[t+m] += w[d]*x[t+m-d]
    }

    float4* yp = (float4*)(y + base + t);
    yp[0] = make_float4(acc[0], acc[1], acc[2], acc[3]);
    yp[1] = make_float4(acc[4], acc[5], acc[6], acc[7]);
}

extern "C" void kernel_launch(void* const* d_in, const int* in_sizes, int n_in,
                              void* d_out, int out_size, void* d_ws, size_t ws_size,
                              hipStream_t stream) {
    const float* x     = (const float*)d_in[0];
    const float* alpha = (const float*)d_in[1];
    const float* beta  = (const float*)d_in[2];
    const float* theta = (const float*)d_in[3];
    float* y = (float*)d_out;
    float* w = (float*)d_ws;                     // 1024*24 floats = 96 KB

    ssm4d_weights<<<(C_CH * KSZ + 255) / 256, 256, 0, stream>>>(alpha, beta, theta, w);

    dim3 grid((T_LEN + TILE - 1) / TILE, B_N * C_CH);   // (3, 16384)
    ssm4d_conv<<<grid, TPB, 0, stream>>>(x, w, y);
}